// Round 4
// baseline (417.815 us; speedup 1.0000x reference)
//
#include <hip/hip_runtime.h>
#include <math.h>

#define ROWLEN 4096
#define BLK 256
#define ROWS_PER_BLOCK 4   // one 64-lane wave per row, 4 independent waves/block

typedef float  vfloat4 __attribute__((ext_vector_type(4)));  // native vec for nontemporal store

__device__ __forceinline__ float med3f(float a, float b, float c) {
    return __builtin_amdgcn_fmed3f(a, b, c);
}
__device__ __forceinline__ float max3f(float a, float b, float c) {
    return fmaxf(fmaxf(a, b), c);   // fuses to v_max3_f32
}
__device__ __forceinline__ float min3f(float a, float b, float c) {
    return fminf(fminf(a, b), c);   // fuses to v_min3_f32
}

// branchless insert of v into sorted-descending triple (t0>=t1>=t2)
__device__ __forceinline__ void ins(float v, float& t0, float& t1, float& t2) {
    float n0 = fmaxf(t0, v);
    float n1 = med3f(t0, t1, v);
    float n2 = fmaxf(t2, fminf(t1, v));
    t0 = n0; t1 = n1; t2 = n2;
}

// branchless merge: (a0,a1,a2) <- top-3 of union of two sorted triples
__device__ __forceinline__ void mrg(float& a0, float& a1, float& a2,
                                    float b0, float b1, float b2) {
    float M  = fmaxf(a1, b1);
    float s  = fminf(a0, b0);
    float o0 = fmaxf(a0, b0);
    float o1 = med3f(a0, b0, M);
    float o2 = max3f(fminf(M, s), a2, b2);
    a0 = o0; a1 = o1; a2 = o2;
}

// exact ordering for the rare-tie fallback (matches jax.lax.top_k)
__device__ __forceinline__ bool better(float v, int i, float w, int j) {
    return (v > w) || (v == w && i < j);
}

__global__ __launch_bounds__(BLK) void topk_softmax_kernel(const float* __restrict__ in,
                                                           float* __restrict__ out) {
    const int lane = threadIdx.x & 63;
    const int wid  = threadIdx.x >> 6;
    const int row  = blockIdx.x * ROWS_PER_BLOCK + wid;

    const float4* rin  = reinterpret_cast<const float4*>(in  + (size_t)row * ROWLEN);
    vfloat4*      rout = reinterpret_cast<vfloat4*>(     out + (size_t)row * ROWLEN);

    // 16 coalesced float4 loads per lane (1 KB/wave-instruction), all in flight
    float4 d[16];
    #pragma unroll
    for (int k = 0; k < 16; ++k) d[k] = rin[lane + 64 * k];

    // per-lane top-3 of 64 values: per-group sort3+ins, then branchless merge
    float t0 = max3f(d[0].x, d[0].y, d[0].z);
    float t1 = med3f(d[0].x, d[0].y, d[0].z);
    float t2 = min3f(d[0].x, d[0].y, d[0].z);
    ins(d[0].w, t0, t1, t2);
    #pragma unroll
    for (int k = 1; k < 16; ++k) {
        float g0 = max3f(d[k].x, d[k].y, d[k].z);
        float g1 = med3f(d[k].x, d[k].y, d[k].z);
        float g2 = min3f(d[k].x, d[k].y, d[k].z);
        ins(d[k].w, g0, g1, g2);
        mrg(t0, t1, t2, g0, g1, g2);
    }

    // 64-lane butterfly: all lanes converge to the row's top-3 values
    #pragma unroll
    for (int off = 1; off < 64; off <<= 1) {
        float b0 = __shfl_xor(t0, off);
        float b1 = __shfl_xor(t1, off);
        float b2 = __shfl_xor(t2, off);
        mrg(t0, t1, t2, b0, b1, b2);
    }
    const float a0 = t0, a1 = t1, a2 = t2;

    // exact row count of (v >= a2) via ballot-popcount (no shuffle chain, no LDS)
    int c = 0;
    #pragma unroll
    for (int k = 0; k < 16; ++k)
        c += (d[k].x >= a2) + (d[k].y >= a2) + (d[k].z >= a2) + (d[k].w >= a2);
    int total = 0;
    #pragma unroll
    for (int b = 0; b < 7; ++b)
        total += (int)__popcll(__ballot((c >> b) & 1)) << b;

    if (total == 3) {
        // fast path: winners are exactly the elements with v >= a2; probs by value.
        // (duplicate values within the triple give equal probs -> value-select exact)
        const float e1   = __expf(a1 - a0);
        const float e2   = __expf(a2 - a0);
        const float invZ = 1.0f / (1.0f + e1 + e2);
        const float p0 = invZ, p1 = e1 * invZ, p2 = e2 * invZ;

        #pragma unroll
        for (int k = 0; k < 16; ++k) {
            const float4 v = d[k];
            vfloat4 o;
            o.x = (v.x < a2) ? 0.0f : (v.x < a1) ? p2 : (v.x < a0) ? p1 : p0;
            o.y = (v.y < a2) ? 0.0f : (v.y < a1) ? p2 : (v.y < a0) ? p1 : p0;
            o.z = (v.z < a2) ? 0.0f : (v.z < a1) ? p2 : (v.z < a0) ? p1 : p0;
            o.w = (v.w < a2) ? 0.0f : (v.w < a1) ? p2 : (v.w < a0) ? p1 : p0;
            __builtin_nontemporal_store(o, &rout[lane + 64 * k]);
        }
    } else {
        // rare exact fallback (tie at rank-3 boundary): wave-local, index tie-break
        float v0 = -INFINITY, v1 = -INFINITY, v2 = -INFINITY;
        int   i0 = 0x7fffffff, i1 = 0x7fffffff, i2 = 0x7fffffff;
        if (lane == 0) {
            const float* r = in + (size_t)row * ROWLEN;
            for (int j = 0; j < ROWLEN; ++j) {
                float v = r[j];
                if (better(v, j, v2, i2)) {
                    if (better(v, j, v1, i1)) {
                        v2 = v1; i2 = i1;
                        if (better(v, j, v0, i0)) { v1 = v0; i1 = i0; v0 = v; i0 = j; }
                        else                      { v1 = v;  i1 = j; }
                    } else { v2 = v; i2 = j; }
                }
            }
        }
        v0 = __shfl(v0, 0); v1 = __shfl(v1, 0); v2 = __shfl(v2, 0);
        i0 = __shfl(i0, 0); i1 = __shfl(i1, 0); i2 = __shfl(i2, 0);
        const float e1 = __expf(v1 - v0), e2 = __expf(v2 - v0);
        const float invZ = 1.0f / (1.0f + e1 + e2);
        const float q0 = invZ, q1 = e1 * invZ, q2 = e2 * invZ;
        #pragma unroll
        for (int k = 0; k < 16; ++k) {
            const int e = 4 * (lane + 64 * k);
            vfloat4 o;
            o.x = (e + 0 == i0) ? q0 : (e + 0 == i1) ? q1 : (e + 0 == i2) ? q2 : 0.0f;
            o.y = (e + 1 == i0) ? q0 : (e + 1 == i1) ? q1 : (e + 1 == i2) ? q2 : 0.0f;
            o.z = (e + 2 == i0) ? q0 : (e + 2 == i1) ? q1 : (e + 2 == i2) ? q2 : 0.0f;
            o.w = (e + 3 == i0) ? q0 : (e + 3 == i1) ? q1 : (e + 3 == i2) ? q2 : 0.0f;
            rout[lane + 64 * k] = o;
        }
    }
}

extern "C" void kernel_launch(void* const* d_in, const int* in_sizes, int n_in,
                              void* d_out, int out_size, void* d_ws, size_t ws_size,
                              hipStream_t stream) {
    const float* in  = (const float*)d_in[0];
    float*       out = (float*)d_out;
    const int rows   = in_sizes[0] / ROWLEN;          // 8*2048 = 16384
    const int blocks = rows / ROWS_PER_BLOCK;         // 4096
    topk_softmax_kernel<<<blocks, BLK, 0, stream>>>(in, out);
}